// Round 7
// baseline (401.211 us; speedup 1.0000x reference)
//
#include <hip/hip_runtime.h>
#include <cstdint>
#include <cstddef>

typedef __attribute__((ext_vector_type(4))) float f32x4;
typedef __attribute__((ext_vector_type(16))) float f32x16;
typedef __attribute__((ext_vector_type(8))) short bf16x8;
typedef __attribute__((ext_vector_type(2))) unsigned int u32x2;

#define S_LEN   2048
#define HID     4096
#define NH      32
#define NKV     8
#define HD      128
#define QKV_N   6144   /* 4096 Q + 1024 K + 1024 V */

typedef const __attribute__((address_space(1))) unsigned int* gptr_t;
typedef __attribute__((address_space(3))) unsigned int* lptr_t;

__device__ __forceinline__ void gload_lds16(const void* g, void* l) {
  __builtin_amdgcn_global_load_lds((gptr_t)g, (lptr_t)l, 16, 0, 0);
}

__device__ __forceinline__ ushort f2bf(float f) {
  union { float f; uint32_t u; } v; v.f = f;
  uint32_t r = v.u + 0x7FFFu + ((v.u >> 16) & 1u);
  return (ushort)(r >> 16);
}
__device__ __forceinline__ float bf2f(ushort u) {
  union { uint32_t u; float f; } v; v.u = ((uint32_t)u) << 16;
  return v.f;
}

// ---------------- cast f32 -> bf16 (vectorized) ----------------
__global__ void cast_f32_bf16(const float* __restrict__ in, ushort* __restrict__ out, int n) {
  int i = (blockIdx.x * 256 + threadIdx.x) * 4;
  if (i >= n) return;
  float4 v = *reinterpret_cast<const float4*>(in + i);
  ushort4 o;
  o.x = f2bf(v.x); o.y = f2bf(v.y); o.z = f2bf(v.z); o.w = f2bf(v.w);
  *reinterpret_cast<ushort4*>(out + i) = o;
}

// ---------------- transpose + cast: in f32 [R][C] -> out bf16 [C][R] ----------------
__global__ void transpose_cast(const float* __restrict__ in, ushort* __restrict__ out, int R, int C) {
  __shared__ float t[32][33];
  int tx = threadIdx.x & 31, ty = threadIdx.x >> 5;  // 32 x 8
  int r0 = blockIdx.y * 32, c0 = blockIdx.x * 32;
#pragma unroll
  for (int i = 0; i < 32; i += 8)
    t[ty + i][tx] = in[(size_t)(r0 + ty + i) * C + c0 + tx];
  __syncthreads();
#pragma unroll
  for (int i = 0; i < 32; i += 8)
    out[(size_t)(c0 + ty + i) * R + r0 + tx] = f2bf(t[tx][ty + i]);
}

// ---------------- ring GEMM: C[M][N] = A[M][K] * B^T (B stored [N][K]), bf16 in, fp32 acc ----
// 128x256 tile, BK=64, 512 threads (8 waves 2Mx4N, per-wave 64x64). 3-buffer LDS ring,
// counted vmcnt (T4): iteration t stages tile t+2, waits vmcnt(12) = tile t landed while
// tiles t+1,t+2 stay in flight (never drain to 0 mid-loop). Raw s_barrier pair per tile:
// (A) after vmcnt -> buf ready for all waves; (B) after ds_read+lgkmcnt(0) -> safe for
// next iteration's overwrite of ring slot (t+3)%3 == t%3.
// LDS chunks XOR-swizzled ch^(row&7) on both stage-source and read (rows are 128B).
template <bool BF16_OUT>
__global__ __launch_bounds__(512, 2) void gemm_ring(
    const ushort* __restrict__ A, const ushort* __restrict__ B,
    void* __restrict__ Cp, int N, int K) {
  __shared__ ushort a_lds[3][128 * 64];
  __shared__ ushort b_lds[3][256 * 64];
  const int tid = threadIdx.x;
  const int wid = tid >> 6, lane = tid & 63;
  const int l16 = lane & 15, lk = lane >> 4;
  const int wr = wid >> 2, wc = wid & 3;
  const size_t a_row0 = (size_t)blockIdx.y * 128;
  const size_t b_row0 = (size_t)blockIdx.x * 256;

  f32x4 acc[4][4] = {};
  const int NT = K >> 6;

  auto stage = [&](int buf, int t) {
    const size_t kb = (size_t)t << 6;
#pragma unroll
    for (int i = 0; i < 2; ++i) {
      int c = i * 512 + tid;                 // A: 1024 16B-chunks (128 rows x 8)
      int row = c >> 3, pos = c & 7, g = pos ^ (row & 7);
      gload_lds16(A + (a_row0 + row) * K + kb + g * 8, &a_lds[buf][c * 8]);
    }
#pragma unroll
    for (int i = 0; i < 4; ++i) {
      int c = i * 512 + tid;                 // B: 2048 chunks (256 rows x 8)
      int row = c >> 3, pos = c & 7, g = pos ^ (row & 7);
      gload_lds16(B + (b_row0 + row) * K + kb + g * 8, &b_lds[buf][c * 8]);
    }
  };

  stage(0, 0);
  stage(1, 1);

  for (int t = 0; t < NT; ++t) {
    const int cur = t % 3;
    if (t + 2 < NT) stage((t + 2) % 3, t + 2);

    // tile t landed (in-order retirement); up to 12 younger loads stay in flight
    if (t < NT - 2)       asm volatile("s_waitcnt vmcnt(12)" ::: "memory");
    else if (t == NT - 2) asm volatile("s_waitcnt vmcnt(6)" ::: "memory");
    else                  asm volatile("s_waitcnt vmcnt(0)" ::: "memory");
    __builtin_amdgcn_s_barrier();            // (A) buf[cur] ready (all waves' DMA landed)

    bf16x8 af[4][2], bfr[4][2];
#pragma unroll
    for (int m = 0; m < 4; ++m) {
      int row = wr * 64 + m * 16 + l16;
#pragma unroll
      for (int kk = 0; kk < 2; ++kk) {
        int c = (kk * 4 + lk) ^ (row & 7);
        af[m][kk] = *reinterpret_cast<const bf16x8*>(&a_lds[cur][row * 64 + c * 8]);
      }
    }
#pragma unroll
    for (int n = 0; n < 4; ++n) {
      int row = wc * 64 + n * 16 + l16;
#pragma unroll
      for (int kk = 0; kk < 2; ++kk) {
        int c = (kk * 4 + lk) ^ (row & 7);
        bfr[n][kk] = *reinterpret_cast<const bf16x8*>(&b_lds[cur][row * 64 + c * 8]);
      }
    }
    asm volatile("s_waitcnt lgkmcnt(0)" ::: "memory");
    __builtin_amdgcn_s_barrier();            // (B) all waves read -> slot reusable next iter

    __builtin_amdgcn_s_setprio(1);
#pragma unroll
    for (int kk = 0; kk < 2; ++kk)
#pragma unroll
      for (int m = 0; m < 4; ++m)
#pragma unroll
        for (int n = 0; n < 4; ++n)
          acc[m][n] = __builtin_amdgcn_mfma_f32_16x16x32_bf16(af[m][kk], bfr[n][kk], acc[m][n], 0, 0, 0);
    __builtin_amdgcn_s_setprio(0);
  }

  // epilogue (verified m97 C/D mapping: col=lane&15, row=(lane>>4)*4+reg)
#pragma unroll
  for (int m = 0; m < 4; ++m) {
    size_t row_b = a_row0 + wr * 64 + m * 16 + lk * 4;
#pragma unroll
    for (int n = 0; n < 4; ++n) {
      int col = (int)b_row0 + wc * 64 + n * 16 + l16;
#pragma unroll
      for (int r = 0; r < 4; ++r) {
        if constexpr (BF16_OUT)
          ((ushort*)Cp)[(row_b + r) * N + col] = f2bf(acc[m][n][r]);
        else
          ((float*)Cp)[(row_b + r) * N + col] = acc[m][n][r];
      }
    }
  }
}

// ---------------- RoPE in-place on Q (cols 0..4095) and K (cols 4096..5119) of QKV ----------------
__global__ void rope_kernel(ushort* __restrict__ QKV) {
  int idx = blockIdx.x * 256 + threadIdx.x;  // 2048 * 40 * 8 threads
  int dg = idx & 7;
  int t = idx >> 3;
  int s = t / 40;
  int hh = t - s * 40;
  if (s >= S_LEN) return;
  int col = (hh < NH) ? hh * HD : HID + (hh - NH) * HD;
  ushort* base = QKV + (size_t)s * QKV_N + col + dg * 8;

  union U { uint4 v; ushort u[8]; };
  U L, H, OL, OH;
  L.v = *reinterpret_cast<const uint4*>(base);
  H.v = *reinterpret_cast<const uint4*>(base + 64);
  const float C0 = 13.287712379549449f / 64.0f;  // log2(10000)/64
#pragma unroll
  for (int j = 0; j < 8; ++j) {
    int d = dg * 8 + j;
    float invf = exp2f(-(float)d * C0);
    float ang = (float)s * invf;
    float sn, cs;
    sincosf(ang, &sn, &cs);
    float xl = bf2f(L.u[j]), xh = bf2f(H.u[j]);
    OL.u[j] = f2bf(xl * cs - xh * sn);
    OH.u[j] = f2bf(xh * cs + xl * sn);
  }
  *reinterpret_cast<uint4*>(base) = OL.v;
  *reinterpret_cast<uint4*>(base + 64) = OH.v;
}

// ---------------- V slice of QKV -> Vt[8][128][2048] ----------------
__global__ void transpose_v(const ushort* __restrict__ QKV, ushort* __restrict__ Vt) {
  __shared__ ushort t[64][65];
  int s0 = blockIdx.x * 64;
  int d0 = blockIdx.y * 64;
  int hkv = blockIdx.z;
  int tx = threadIdx.x & 63, ty = threadIdx.x >> 6;  // 64 x 4
#pragma unroll
  for (int i = 0; i < 64; i += 4)
    t[i + ty][tx] = QKV[(size_t)(s0 + i + ty) * QKV_N + HID + NKV * HD + hkv * HD + d0 + tx];
  __syncthreads();
#pragma unroll
  for (int i = 0; i < 64; i += 4)
    Vt[((size_t)hkv * HD + d0 + i + ty) * S_LEN + s0 + tx] = t[tx][i + ty];
}

// ---------------- flash attention: swapped-QK^T 32x32 MFMA, in-register softmax ----------------
__global__ __launch_bounds__(256, 2) void attn_kernel(
    const ushort* __restrict__ QKV, const ushort* __restrict__ Vt, ushort* __restrict__ AO) {
  constexpr float SCALE = 0.08838834764831845f;  // 1/sqrt(128)
  __shared__ ushort k_lds[2][64 * 128];   // [krow][128 d], 16B chunks XOR-swizzled by (row&7)
  __shared__ ushort v_lds[2][128 * 64];   // [d][64 s], 16B chunks XOR-swizzled by (row&7)

  const int qb = blockIdx.x;              // 0..15
  const int h = blockIdx.y;
  const int hkv = h >> 2;
  const int q0 = qb * 128;
  const int tid = threadIdx.x, wid = tid >> 6, lane = tid & 63;
  const int l32 = lane & 31;
  const int hi = lane >> 5;
  const int qg = q0 + wid * 32 + l32;     // this lane's q row

  bf16x8 qf[8];
  {
    const ushort* qrow = QKV + (size_t)qg * QKV_N + h * HD + hi * 8;
#pragma unroll
    for (int ds = 0; ds < 8; ++ds)
      qf[ds] = *reinterpret_cast<const bf16x8*>(qrow + ds * 16);
  }

  float m_run = -1e30f, l_run = 0.f;
  f32x16 oacc[4] = {};   // oacc[f][r] = O[q=l32][d = f*32 + crow(r,hi)]

  auto stageKV = [&](int buf, int kt) {
#pragma unroll
    for (int i = 0; i < 4; ++i) {
      int c = i * 256 + wid * 64 + lane;
      int row = c >> 4, ch = c & 15;
      int sch = ch ^ (row & 7);
      gload_lds16(QKV + (size_t)(kt * 64 + row) * QKV_N + HID + hkv * HD + sch * 8,
                  &k_lds[buf][c * 8]);
    }
#pragma unroll
    for (int i = 0; i < 4; ++i) {
      int c = i * 256 + wid * 64 + lane;
      int row = c >> 3, ch = c & 7;
      int sch = ch ^ (row & 7);
      gload_lds16(Vt + ((size_t)hkv * HD + row) * S_LEN + (size_t)kt * 64 + sch * 8,
                  &v_lds[buf][c * 8]);
    }
  };

  stageKV(0, 0);
  __syncthreads();

  const int nt = 2 * qb + 2;
  for (int kt = 0; kt < nt; ++kt) {
    const int cur = kt & 1;
    if (kt + 1 < nt) stageKV(cur ^ 1, kt + 1);

    if (kt * 64 <= q0 + wid * 32 + 31) {
      float p[32];
      __builtin_amdgcn_s_setprio(1);
#pragma unroll
      for (int kf = 0; kf < 2; ++kf) {
        f32x16 s = {};
        int rk = kf * 32 + l32;
#pragma unroll
        for (int ds = 0; ds < 8; ++ds) {
          int c16 = (ds * 2 + hi) ^ (rk & 7);
          bf16x8 kfr = *reinterpret_cast<const bf16x8*>(&k_lds[cur][rk * 128 + c16 * 8]);
          s = __builtin_amdgcn_mfma_f32_32x32x16_bf16(kfr, qf[ds], s, 0, 0, 0);
        }
#pragma unroll
        for (int r = 0; r < 16; ++r) p[kf * 16 + r] = s[r] * SCALE;
      }
      __builtin_amdgcn_s_setprio(0);

      if (kt * 64 + 63 > q0 + wid * 32) {
#pragma unroll
        for (int kf = 0; kf < 2; ++kf)
#pragma unroll
          for (int r = 0; r < 16; ++r) {
            int kl = kf * 32 + (r & 3) + 8 * (r >> 2) + 4 * hi;
            if (kt * 64 + kl > qg) p[kf * 16 + r] = -1e30f;
          }
      }

      float mt = p[0];
#pragma unroll
      for (int i = 1; i < 32; ++i) mt = fmaxf(mt, p[i]);
      mt = fmaxf(mt, __shfl_xor(mt, 32, 64));
      float mn = fmaxf(m_run, mt);
      float alpha = __expf(m_run - mn);
      float ls = 0.f;
#pragma unroll
      for (int i = 0; i < 32; ++i) { p[i] = __expf(p[i] - mn); ls += p[i]; }
      ls += __shfl_xor(ls, 32, 64);
      l_run = l_run * alpha + ls;
      m_run = mn;
#pragma unroll
      for (int f = 0; f < 4; ++f)
#pragma unroll
        for (int r = 0; r < 16; ++r) oacc[f][r] *= alpha;

      union PW { uint32_t w[4]; bf16x8 v; } pa[4];
#pragma unroll
      for (int ks = 0; ks < 4; ++ks) {
        uint32_t x0, x1, y0, y1;
        asm("v_cvt_pk_bf16_f32 %0, %1, %2" : "=v"(x0) : "v"(p[8 * ks + 0]), "v"(p[8 * ks + 1]));
        asm("v_cvt_pk_bf16_f32 %0, %1, %2" : "=v"(x1) : "v"(p[8 * ks + 2]), "v"(p[8 * ks + 3]));
        asm("v_cvt_pk_bf16_f32 %0, %1, %2" : "=v"(y0) : "v"(p[8 * ks + 4]), "v"(p[8 * ks + 5]));
        asm("v_cvt_pk_bf16_f32 %0, %1, %2" : "=v"(y1) : "v"(p[8 * ks + 6]), "v"(p[8 * ks + 7]));
        u32x2 r0 = __builtin_amdgcn_permlane32_swap(x0, y0, false, false);
        u32x2 r1 = __builtin_amdgcn_permlane32_swap(x1, y1, false, false);
        pa[ks].w[0] = r0.x; pa[ks].w[1] = r1.x; pa[ks].w[2] = r0.y; pa[ks].w[3] = r1.y;
      }

      __builtin_amdgcn_s_setprio(1);
#pragma unroll
      for (int ks = 0; ks < 4; ++ks) {
#pragma unroll
        for (int f = 0; f < 4; ++f) {
          int dv = f * 32 + l32;
          int c8 = (2 * ks + hi) ^ (dv & 7);
          bf16x8 vfr = *reinterpret_cast<const bf16x8*>(&v_lds[cur][dv * 64 + c8 * 8]);
          oacc[f] = __builtin_amdgcn_mfma_f32_32x32x16_bf16(vfr, pa[ks].v, oacc[f], 0, 0, 0);
        }
      }
      __builtin_amdgcn_s_setprio(0);
    }

    __syncthreads();
  }

  float inv_l = 1.0f / l_run;
  ushort* aorow = AO + (size_t)qg * HID + h * HD;
#pragma unroll
  for (int f = 0; f < 4; ++f)
#pragma unroll
    for (int g = 0; g < 4; ++g) {
      ushort4 o;
      o.x = f2bf(oacc[f][g * 4 + 0] * inv_l);
      o.y = f2bf(oacc[f][g * 4 + 1] * inv_l);
      o.z = f2bf(oacc[f][g * 4 + 2] * inv_l);
      o.w = f2bf(oacc[f][g * 4 + 3] * inv_l);
      *reinterpret_cast<ushort4*>(aorow + f * 32 + g * 8 + 4 * hi) = o;
    }
}

// ---------------- launcher ----------------
extern "C" void kernel_launch(void* const* d_in, const int* in_sizes, int n_in,
                              void* d_out, int out_size, void* d_ws, size_t ws_size,
                              hipStream_t stream) {
  (void)in_sizes; (void)n_in; (void)out_size;
  const float* hs = (const float*)d_in[0];
  const float* Wq = (const float*)d_in[1];
  const float* Wk = (const float*)d_in[2];
  const float* Wv = (const float*)d_in[3];
  const float* Wo = (const float*)d_in[4];
  float* out = (float*)d_out;

  // workspace layout (bytes)
  char* ws = (char*)d_ws;
  const size_t OFF_HSB   = 0;                         // 2048*4096 bf16 = 16 MB
  const size_t OFF_WQKVT = OFF_HSB + 16777216;        // 6144*4096 bf16 = 48 MB
  const size_t OFF_WOT   = OFF_WQKVT + 50331648;      // 4096*4096 bf16 = 32 MB
  const size_t OFF_QKV   = OFF_WOT + 33554432;        // 2048*6144 bf16 = 24 MB
  const size_t OFF_VT    = OFF_QKV + 25165824;        // 8*128*2048 bf16 = 4 MB
  const size_t OFF_AO    = OFF_VT + 4194304;          // 2048*4096 bf16 = 16 MB
  if (ws_size < OFF_AO + 16777216) return;            // ~140 MB needed

  ushort* hsb   = (ushort*)(ws + OFF_HSB);
  ushort* WqkvT = (ushort*)(ws + OFF_WQKVT);
  ushort* WoT   = (ushort*)(ws + OFF_WOT);
  ushort* QKV   = (ushort*)(ws + OFF_QKV);
  ushort* Vt    = (ushort*)(ws + OFF_VT);
  ushort* AO    = (ushort*)(ws + OFF_AO);

  cast_f32_bf16<<<8192, 256, 0, stream>>>(hs, hsb, S_LEN * HID);
  transpose_cast<<<dim3(4096 / 32, 4096 / 32), 256, 0, stream>>>(Wq, WqkvT, HID, 4096);
  transpose_cast<<<dim3(1024 / 32, 4096 / 32), 256, 0, stream>>>(Wk, WqkvT + (size_t)4096 * HID, HID, 1024);
  transpose_cast<<<dim3(1024 / 32, 4096 / 32), 256, 0, stream>>>(Wv, WqkvT + (size_t)5120 * HID, HID, 1024);
  transpose_cast<<<dim3(4096 / 32, 4096 / 32), 256, 0, stream>>>(Wo, WoT, 4096, HID);

  gemm_ring<true><<<dim3(QKV_N / 256, S_LEN / 128), 512, 0, stream>>>(hsb, WqkvT, QKV, QKV_N, HID);
  rope_kernel<<<(S_LEN * 40 * 8) / 256, 256, 0, stream>>>(QKV);
  transpose_v<<<dim3(S_LEN / 64, HD / 64, NKV), 256, 0, stream>>>(QKV, Vt);
  attn_kernel<<<dim3(S_LEN / 128, NH), 256, 0, stream>>>(QKV, Vt, AO);
  gemm_ring<false><<<dim3(HID / 256, S_LEN / 128), 512, 0, stream>>>(AO, WoT, out, HID, HID);
}

// Round 8
// 355.078 us; speedup vs baseline: 1.1299x; 1.1299x over previous
//
#include <hip/hip_runtime.h>
#include <cstdint>
#include <cstddef>

typedef __attribute__((ext_vector_type(4))) float f32x4;
typedef __attribute__((ext_vector_type(16))) float f32x16;
typedef __attribute__((ext_vector_type(8))) short bf16x8;
typedef __attribute__((ext_vector_type(2))) unsigned int u32x2;

#define S_LEN   2048
#define HID     4096
#define NH      32
#define NKV     8
#define HD      128
#define QKV_N   6144   /* 4096 Q + 1024 K + 1024 V */

typedef const __attribute__((address_space(1))) unsigned int* gptr_t;
typedef __attribute__((address_space(3))) unsigned int* lptr_t;

__device__ __forceinline__ void gload_lds16(const void* g, void* l) {
  __builtin_amdgcn_global_load_lds((gptr_t)g, (lptr_t)l, 16, 0, 0);
}

__device__ __forceinline__ ushort f2bf(float f) {
  union { float f; uint32_t u; } v; v.f = f;
  uint32_t r = v.u + 0x7FFFu + ((v.u >> 16) & 1u);
  return (ushort)(r >> 16);
}
__device__ __forceinline__ float bf2f(ushort u) {
  union { uint32_t u; float f; } v; v.u = ((uint32_t)u) << 16;
  return v.f;
}

// ---------------- cast f32 -> bf16 (vectorized) ----------------
__global__ void cast_f32_bf16(const float* __restrict__ in, ushort* __restrict__ out, int n) {
  int i = (blockIdx.x * 256 + threadIdx.x) * 4;
  if (i >= n) return;
  float4 v = *reinterpret_cast<const float4*>(in + i);
  ushort4 o;
  o.x = f2bf(v.x); o.y = f2bf(v.y); o.z = f2bf(v.z); o.w = f2bf(v.w);
  *reinterpret_cast<ushort4*>(out + i) = o;
}

// ---------------- transpose + cast: in f32 [R][C] -> out bf16 [C][R] ----------------
__global__ void transpose_cast(const float* __restrict__ in, ushort* __restrict__ out, int R, int C) {
  __shared__ float t[32][33];
  int tx = threadIdx.x & 31, ty = threadIdx.x >> 5;  // 32 x 8
  int r0 = blockIdx.y * 32, c0 = blockIdx.x * 32;
#pragma unroll
  for (int i = 0; i < 32; i += 8)
    t[ty + i][tx] = in[(size_t)(r0 + ty + i) * C + c0 + tx];
  __syncthreads();
#pragma unroll
  for (int i = 0; i < 32; i += 8)
    out[(size_t)(c0 + ty + i) * R + r0 + tx] = f2bf(t[tx][ty + i]);
}

// ---------------- GEMM: C[M][N] = A[M][K] * B^T  (B stored [N][K]), bf16 in, fp32 acc ----------------
// m97 structure: 128x128 tile, BK=32, 4 waves (2x2), each wave 64x64 (4x4 frags of 16x16x32).
// (R6-measured: QKV 129-132us / ~805 TF. Deep-pipeline variants R5/R7 regressed: big-LDS
//  kills the multi-block-per-CU overlap that hides the barrier drain. Keep this.)
template <bool BF16_OUT>
__global__ __launch_bounds__(256, 4) void gemm_bt(
    const ushort* __restrict__ A, const ushort* __restrict__ B,
    void* __restrict__ Cp, int M, int N, int K) {
  __shared__ ushort a_lds[128 * 32];
  __shared__ ushort b_lds[128 * 32];
  const int tid = threadIdx.x;
  const int wid = tid >> 6, lane = tid & 63;
  const int l16 = lane & 15, lk = lane >> 4;
  const int wr = wid >> 1, wc = wid & 1;
  const size_t a_row0 = (size_t)blockIdx.y * 128;
  const size_t b_row0 = (size_t)blockIdx.x * 128;

  f32x4 acc[4][4] = {};
  const int pswz = lk ^ (l16 & 3) ^ ((l16 >> 2) & 1);

  for (int kt = 0; kt < K; kt += 32) {
    __syncthreads();
#pragma unroll
    for (int i = 0; i < 2; ++i) {
      int c = i * 256 + tid;
      int row = c >> 2, p = c & 3;
      int gch = p ^ (row & 3) ^ ((row >> 2) & 1);
      gload_lds16(A + (a_row0 + row) * K + kt + gch * 8, &a_lds[c * 8]);
      gload_lds16(B + (b_row0 + row) * K + kt + gch * 8, &b_lds[c * 8]);
    }
    __syncthreads();

    bf16x8 af[4], bf[4];
#pragma unroll
    for (int m = 0; m < 4; ++m) {
      int row = wr * 64 + m * 16 + l16;
      af[m] = *reinterpret_cast<const bf16x8*>(&a_lds[row * 32 + pswz * 8]);
    }
#pragma unroll
    for (int n = 0; n < 4; ++n) {
      int row = wc * 64 + n * 16 + l16;
      bf[n] = *reinterpret_cast<const bf16x8*>(&b_lds[row * 32 + pswz * 8]);
    }
#pragma unroll
    for (int m = 0; m < 4; ++m)
#pragma unroll
      for (int n = 0; n < 4; ++n)
        acc[m][n] = __builtin_amdgcn_mfma_f32_16x16x32_bf16(af[m], bf[n], acc[m][n], 0, 0, 0);
  }

#pragma unroll
  for (int m = 0; m < 4; ++m) {
    int row_b = wr * 64 + m * 16 + lk * 4;
#pragma unroll
    for (int n = 0; n < 4; ++n) {
      int col = (int)b_row0 + wc * 64 + n * 16 + l16;
#pragma unroll
      for (int r = 0; r < 4; ++r) {
        size_t row = a_row0 + row_b + r;
        if constexpr (BF16_OUT)
          ((ushort*)Cp)[row * N + col] = f2bf(acc[m][n][r]);
        else
          ((float*)Cp)[row * N + col] = acc[m][n][r];
      }
    }
  }
}

// ---------------- RoPE in-place on Q (cols 0..4095) and K (cols 4096..5119) of QKV ----------------
__global__ void rope_kernel(ushort* __restrict__ QKV) {
  int idx = blockIdx.x * 256 + threadIdx.x;  // 2048 * 40 * 8 threads
  int dg = idx & 7;
  int t = idx >> 3;
  int s = t / 40;
  int hh = t - s * 40;
  if (s >= S_LEN) return;
  int col = (hh < NH) ? hh * HD : HID + (hh - NH) * HD;
  ushort* base = QKV + (size_t)s * QKV_N + col + dg * 8;

  union U { uint4 v; ushort u[8]; };
  U L, H, OL, OH;
  L.v = *reinterpret_cast<const uint4*>(base);
  H.v = *reinterpret_cast<const uint4*>(base + 64);
  const float C0 = 13.287712379549449f / 64.0f;  // log2(10000)/64
#pragma unroll
  for (int j = 0; j < 8; ++j) {
    int d = dg * 8 + j;
    float invf = exp2f(-(float)d * C0);
    float ang = (float)s * invf;
    float sn, cs;
    sincosf(ang, &sn, &cs);
    float xl = bf2f(L.u[j]), xh = bf2f(H.u[j]);
    OL.u[j] = f2bf(xl * cs - xh * sn);
    OH.u[j] = f2bf(xh * cs + xl * sn);
  }
  *reinterpret_cast<uint4*>(base) = OL.v;
  *reinterpret_cast<uint4*>(base + 64) = OH.v;
}

// ---------------- V slice of QKV -> Vt[8][128][2048] ----------------
__global__ void transpose_v(const ushort* __restrict__ QKV, ushort* __restrict__ Vt) {
  __shared__ ushort t[64][65];
  int s0 = blockIdx.x * 64;
  int d0 = blockIdx.y * 64;
  int hkv = blockIdx.z;
  int tx = threadIdx.x & 63, ty = threadIdx.x >> 6;  // 64 x 4
#pragma unroll
  for (int i = 0; i < 64; i += 4)
    t[i + ty][tx] = QKV[(size_t)(s0 + i + ty) * QKV_N + HID + NKV * HD + hkv * HD + d0 + tx];
  __syncthreads();
#pragma unroll
  for (int i = 0; i < 64; i += 4)
    Vt[((size_t)hkv * HD + d0 + i + ty) * S_LEN + s0 + tx] = t[tx][i + ty];
}

// ---------------- flash attention: swapped-QK^T 32x32 MFMA, in-register softmax ----------------
// Grid = 256 blocks (one full-chip round). Block lin decodes:
//   xcd-slot = lin&7, h = (lin&7)*4 + ((lin>>3)&3), p = lin>>5.
// Uniform causal load: block processes q-panels {p, 15-p} -> exactly 34 KV-tiles each.
// XCD-local KV: with round-robin block->XCD, XCD x serves only hkv=x (K+V = 1MB, fits 4MB L2).
__global__ __launch_bounds__(256, 2) void attn_kernel(
    const ushort* __restrict__ QKV, const ushort* __restrict__ Vt, ushort* __restrict__ AO) {
  constexpr float SCALE = 0.08838834764831845f;  // 1/sqrt(128)
  __shared__ ushort k_lds[2][64 * 128];   // [krow][128 d], 16B chunks XOR-swizzled by (row&7)
  __shared__ ushort v_lds[2][128 * 64];   // [d][64 s], 16B chunks XOR-swizzled by (row&7)

  const int lin = blockIdx.x;
  const int h = ((lin & 7) << 2) + ((lin >> 3) & 3);
  const int p = lin >> 5;                 // 0..7
  const int hkv = h >> 2;
  const int tid = threadIdx.x, wid = tid >> 6, lane = tid & 63;
  const int l32 = lane & 31;
  const int hi = lane >> 5;

  auto stageKV = [&](int buf, int kt) {
#pragma unroll
    for (int i = 0; i < 4; ++i) {
      int c = i * 256 + wid * 64 + lane;
      int row = c >> 4, ch = c & 15;
      int sch = ch ^ (row & 7);
      gload_lds16(QKV + (size_t)(kt * 64 + row) * QKV_N + HID + hkv * HD + sch * 8,
                  &k_lds[buf][c * 8]);
    }
#pragma unroll
    for (int i = 0; i < 4; ++i) {
      int c = i * 256 + wid * 64 + lane;
      int row = c >> 3, ch = c & 7;
      int sch = ch ^ (row & 7);
      gload_lds16(Vt + ((size_t)hkv * HD + row) * S_LEN + (size_t)kt * 64 + sch * 8,
                  &v_lds[buf][c * 8]);
    }
  };

  for (int pi = 0; pi < 2; ++pi) {
    const int qb = pi ? (15 - p) : p;
    const int q0 = qb * 128;
    const int qg = q0 + wid * 32 + l32;   // this lane's q row

    bf16x8 qf[8];
    {
      const ushort* qrow = QKV + (size_t)qg * QKV_N + h * HD + hi * 8;
#pragma unroll
      for (int ds = 0; ds < 8; ++ds)
        qf[ds] = *reinterpret_cast<const bf16x8*>(qrow + ds * 16);
    }

    float m_run = -1e30f, l_run = 0.f;
    f32x16 oacc[4] = {};   // oacc[f][r] = O[q=l32][d = f*32 + crow(r,hi)]

    stageKV(0, 0);
    __syncthreads();

    const int nt = 2 * qb + 2;
    for (int kt = 0; kt < nt; ++kt) {
      const int cur = kt & 1;
      if (kt + 1 < nt) stageKV(cur ^ 1, kt + 1);

      if (kt * 64 <= q0 + wid * 32 + 31) {
        float pv[32];
        __builtin_amdgcn_s_setprio(1);
#pragma unroll
        for (int kf = 0; kf < 2; ++kf) {
          f32x16 s = {};
          int rk = kf * 32 + l32;
#pragma unroll
          for (int ds = 0; ds < 8; ++ds) {
            int c16 = (ds * 2 + hi) ^ (rk & 7);
            bf16x8 kfr = *reinterpret_cast<const bf16x8*>(&k_lds[cur][rk * 128 + c16 * 8]);
            s = __builtin_amdgcn_mfma_f32_32x32x16_bf16(kfr, qf[ds], s, 0, 0, 0);
          }
#pragma unroll
          for (int r = 0; r < 16; ++r) pv[kf * 16 + r] = s[r] * SCALE;
        }
        __builtin_amdgcn_s_setprio(0);

        if (kt * 64 + 63 > q0 + wid * 32) {  // diagonal tile: causal mask
#pragma unroll
          for (int kf = 0; kf < 2; ++kf)
#pragma unroll
            for (int r = 0; r < 16; ++r) {
              int kl = kf * 32 + (r & 3) + 8 * (r >> 2) + 4 * hi;
              if (kt * 64 + kl > qg) pv[kf * 16 + r] = -1e30f;
            }
        }

        float mt = pv[0];
#pragma unroll
        for (int i = 1; i < 32; ++i) mt = fmaxf(mt, pv[i]);
        mt = fmaxf(mt, __shfl_xor(mt, 32, 64));
        float mn = fmaxf(m_run, mt);
        float alpha = __expf(m_run - mn);
        float ls = 0.f;
#pragma unroll
        for (int i = 0; i < 32; ++i) { pv[i] = __expf(pv[i] - mn); ls += pv[i]; }
        ls += __shfl_xor(ls, 32, 64);
        l_run = l_run * alpha + ls;
        m_run = mn;
#pragma unroll
        for (int f = 0; f < 4; ++f)
#pragma unroll
          for (int r = 0; r < 16; ++r) oacc[f][r] *= alpha;

        // pack P -> PV B-operand (T12: cvt_pk + permlane32_swap)
        union PW { uint32_t w[4]; bf16x8 v; } pa[4];
#pragma unroll
        for (int ks = 0; ks < 4; ++ks) {
          uint32_t x0, x1, y0, y1;
          asm("v_cvt_pk_bf16_f32 %0, %1, %2" : "=v"(x0) : "v"(pv[8 * ks + 0]), "v"(pv[8 * ks + 1]));
          asm("v_cvt_pk_bf16_f32 %0, %1, %2" : "=v"(x1) : "v"(pv[8 * ks + 2]), "v"(pv[8 * ks + 3]));
          asm("v_cvt_pk_bf16_f32 %0, %1, %2" : "=v"(y0) : "v"(pv[8 * ks + 4]), "v"(pv[8 * ks + 5]));
          asm("v_cvt_pk_bf16_f32 %0, %1, %2" : "=v"(y1) : "v"(pv[8 * ks + 6]), "v"(pv[8 * ks + 7]));
          u32x2 r0 = __builtin_amdgcn_permlane32_swap(x0, y0, false, false);
          u32x2 r1 = __builtin_amdgcn_permlane32_swap(x1, y1, false, false);
          pa[ks].w[0] = r0.x; pa[ks].w[1] = r1.x; pa[ks].w[2] = r0.y; pa[ks].w[3] = r1.y;
        }

        __builtin_amdgcn_s_setprio(1);
#pragma unroll
        for (int ks = 0; ks < 4; ++ks) {
#pragma unroll
          for (int f = 0; f < 4; ++f) {
            int dv = f * 32 + l32;
            int c8 = (2 * ks + hi) ^ (dv & 7);
            bf16x8 vfr = *reinterpret_cast<const bf16x8*>(&v_lds[cur][dv * 64 + c8 * 8]);
            oacc[f] = __builtin_amdgcn_mfma_f32_32x32x16_bf16(vfr, pa[ks].v, oacc[f], 0, 0, 0);
          }
        }
        __builtin_amdgcn_s_setprio(0);
      }

      __syncthreads();
    }

    float inv_l = 1.0f / l_run;
    ushort* aorow = AO + (size_t)qg * HID + h * HD;
#pragma unroll
    for (int f = 0; f < 4; ++f)
#pragma unroll
      for (int g = 0; g < 4; ++g) {
        ushort4 o;
        o.x = f2bf(oacc[f][g * 4 + 0] * inv_l);
        o.y = f2bf(oacc[f][g * 4 + 1] * inv_l);
        o.z = f2bf(oacc[f][g * 4 + 2] * inv_l);
        o.w = f2bf(oacc[f][g * 4 + 3] * inv_l);
        *reinterpret_cast<ushort4*>(aorow + f * 32 + g * 8 + 4 * hi) = o;
      }
  }
}

// ---------------- launcher ----------------
extern "C" void kernel_launch(void* const* d_in, const int* in_sizes, int n_in,
                              void* d_out, int out_size, void* d_ws, size_t ws_size,
                              hipStream_t stream) {
  (void)in_sizes; (void)n_in; (void)out_size;
  const float* hs = (const float*)d_in[0];
  const float* Wq = (const float*)d_in[1];
  const float* Wk = (const float*)d_in[2];
  const float* Wv = (const float*)d_in[3];
  const float* Wo = (const float*)d_in[4];
  float* out = (float*)d_out;

  // workspace layout (bytes)
  char* ws = (char*)d_ws;
  const size_t OFF_HSB   = 0;                         // 2048*4096 bf16 = 16 MB
  const size_t OFF_WQKVT = OFF_HSB + 16777216;        // 6144*4096 bf16 = 48 MB
  const size_t OFF_WOT   = OFF_WQKVT + 50331648;      // 4096*4096 bf16 = 32 MB
  const size_t OFF_QKV   = OFF_WOT + 33554432;        // 2048*6144 bf16 = 24 MB
  const size_t OFF_VT    = OFF_QKV + 25165824;        // 8*128*2048 bf16 = 4 MB
  const size_t OFF_AO    = OFF_VT + 4194304;          // 2048*4096 bf16 = 16 MB
  if (ws_size < OFF_AO + 16777216) return;            // ~140 MB needed

  ushort* hsb   = (ushort*)(ws + OFF_HSB);
  ushort* WqkvT = (ushort*)(ws + OFF_WQKVT);
  ushort* WoT   = (ushort*)(ws + OFF_WOT);
  ushort* QKV   = (ushort*)(ws + OFF_QKV);
  ushort* Vt    = (ushort*)(ws + OFF_VT);
  ushort* AO    = (ushort*)(ws + OFF_AO);

  cast_f32_bf16<<<8192, 256, 0, stream>>>(hs, hsb, S_LEN * HID);
  transpose_cast<<<dim3(4096 / 32, 4096 / 32), 256, 0, stream>>>(Wq, WqkvT, HID, 4096);
  transpose_cast<<<dim3(1024 / 32, 4096 / 32), 256, 0, stream>>>(Wk, WqkvT + (size_t)4096 * HID, HID, 1024);
  transpose_cast<<<dim3(1024 / 32, 4096 / 32), 256, 0, stream>>>(Wv, WqkvT + (size_t)5120 * HID, HID, 1024);
  transpose_cast<<<dim3(4096 / 32, 4096 / 32), 256, 0, stream>>>(Wo, WoT, 4096, HID);

  gemm_bt<true><<<dim3(QKV_N / 128, S_LEN / 128), 256, 0, stream>>>(hsb, WqkvT, QKV, S_LEN, QKV_N, HID);
  rope_kernel<<<(S_LEN * 40 * 8) / 256, 256, 0, stream>>>(QKV);
  transpose_v<<<dim3(S_LEN / 64, HD / 64, NKV), 256, 0, stream>>>(QKV, Vt);
  attn_kernel<<<256, 256, 0, stream>>>(QKV, Vt, AO);
  gemm_bt<false><<<dim3(HID / 128, S_LEN / 128), 256, 0, stream>>>(AO, WoT, out, S_LEN, HID, HID);
}